// Round 2
// baseline (253.273 us; speedup 1.0000x reference)
//
#include <hip/hip_runtime.h>
#include <math.h>

#define LOG2E 1.4426950408889634f

__device__ __forceinline__ float rl(float v, int lane) {
  return __builtin_bit_cast(float, __builtin_amdgcn_readlane(__builtin_bit_cast(int, v), lane));
}
template<int CTRL>
__device__ __forceinline__ float dppb(float x) {
  return __builtin_bit_cast(float, __builtin_amdgcn_update_dpp(
      0, __builtin_bit_cast(int, x), CTRL, 0xF, 0xF, true));
}
__device__ __forceinline__ float fexp2(float x){ return __builtin_amdgcn_exp2f(x); }
__device__ __forceinline__ float frcp(float x){ return __builtin_amdgcn_rcpf(x); }
__device__ __forceinline__ float sigm(float x){ return frcp(1.f + fexp2(-LOG2E*x)); }
__device__ __forceinline__ float tanhf_(float x){ return fmaf(frcp(1.f + fexp2(-2.f*LOG2E*x)), 2.f, -1.f); }

// ---------------------------------------------------------------------------
// Kernel 1: merged scene biLSTM (8 steps) + a0 + edge-LSTM (1024-step serial
// recurrence, THE critical path). One wave per batch element. Quad-lane
// layout: lane 4k+q = gate q of hidden unit k. Nonlinearity scale folded into
// weights. Edge loop software-pipelines the pose LDS read and splits the
// h-dot into 4 short FMA chains.
// ---------------------------------------------------------------------------
__global__ __launch_bounds__(64) void enc_kernel(
    const float* __restrict__ scene,
    const float* __restrict__ nw_f, const float* __restrict__ nu_f,
    const float* __restrict__ nbi_f, const float* __restrict__ nbh_f,
    const float* __restrict__ nw_b, const float* __restrict__ nu_b,
    const float* __restrict__ nbi_b, const float* __restrict__ nbh_b,
    const float* __restrict__ ew_f, const float* __restrict__ eu_f,
    const float* __restrict__ ebi_f, const float* __restrict__ ebh_f,
    const float* __restrict__ ew_b, const float* __restrict__ eu_b,
    const float* __restrict__ ebi_b, const float* __restrict__ ebh_b,
    const float* __restrict__ aw, const float* __restrict__ ab,
    float* __restrict__ catted, float* __restrict__ a0)
{
  __shared__ float2 pbuf[1024];
  const int b = blockIdx.x;
  const int l = threadIdx.x;

  // stage all last-timestep poses (uncoalesced but L2-cached; prologue only)
  for (int t = l; t < 1024; t += 64)
    pbuf[t] = *(const float2*)(scene + t*32 + 28);

  if (l < 2) {
    float acc = ab[l];
    #pragma unroll
    for (int jj = 0; jj < 4; jj++) acc = fmaf(scene[b*32 + 28 + jj], aw[l*4 + jj], acc);
    a0[b*2 + l] = acc;
  }

  const int k = l >> 2, q = l & 3;
  const int row = (l < 40) ? (q*10 + k) : 0;
  const float m  = (q == 2) ? (-2.f*LOG2E) : (-LOG2E);
  const float aa = (q == 2) ? 2.f : 1.f;
  const float bb = (q == 2) ? -1.f : 0.f;

  // ---- scene biLSTM (writes catted rows 0..159) ----
  #pragma unroll
  for (int dir = 0; dir < 2; dir++) {
    const float* W  = dir ? nw_b  : nw_f;
    const float* U  = dir ? nu_b  : nu_f;
    const float* BI = dir ? nbi_b : nbi_f;
    const float* BH = dir ? nbh_b : nbh_f;
    float wi[4], wh[10];
    #pragma unroll
    for (int jj = 0; jj < 4; jj++)  wi[jj] = W[row*4 + jj] * m;
    #pragma unroll
    for (int jj = 0; jj < 10; jj++) wh[jj] = U[row*10 + jj] * m;
    const float cst = (BI[row] + BH[row]) * m;
    float c = 0.f, h = 0.f;
    for (int tt = 0; tt < 8; tt++) {
      const int t = dir ? (7 - tt) : tt;
      const float4 x = *(const float4*)(scene + b*32 + t*4);
      float g0 = fmaf(x.x, wi[0], cst);
      float g1 = x.y * wi[1];
      g0 = fmaf(x.z, wi[2], g0);
      g1 = fmaf(x.w, wi[3], g1);
      #pragma unroll
      for (int kk = 0; kk < 10; kk++) {
        const float hk = rl(h, 4*kk);
        if (kk & 1) g1 = fmaf(hk, wh[kk], g1); else g0 = fmaf(hk, wh[kk], g0);
      }
      float s = fmaf(frcp(1.f + fexp2(g0 + g1)), aa, bb);
      const float si = dppb<0x00>(s);
      const float sf = dppb<0x55>(s);
      const float tg = dppb<0xAA>(s);
      const float so = dppb<0xFF>(s);
      c = fmaf(sf, c, si*tg);
      h = so * tanhf_(c);
      if (q == 0 && l < 40) catted[b*180 + t*20 + dir*10 + k] = h;
    }
  }

  // ---- edge LSTM forward: 1024 serial steps ----
  const float pix = scene[b*32 + 28], piy = scene[b*32 + 29];
  const float wxs = ew_f[row*2]   * m;
  const float wys = ew_f[row*2+1] * m;
  float wh[10];
  #pragma unroll
  for (int jj = 0; jj < 10; jj++) wh[jj] = eu_f[row*10 + jj] * m;
  const float cst = fmaf(-pix, wxs, fmaf(-piy, wys, (ebi_f[row] + ebh_f[row]) * m));
  const float km2 = -2.f*LOG2E;

  __syncthreads();

  float c = 0.f, h = 0.f;
  float2 pj = pbuf[0];
  #pragma unroll 4
  for (int j = 0; j < 1024; j++) {
    const float2 pjn = pbuf[(j+1) & 1023];   // software-pipelined, off-chain
    float g0 = fmaf(pj.x, wxs, cst);
    float g1 = pj.y * wys;
    const float h0 = rl(h, 0),  h1 = rl(h, 4),  h2 = rl(h, 8),  h3 = rl(h, 12);
    const float h4_ = rl(h, 16), h5 = rl(h, 20), h6 = rl(h, 24), h7 = rl(h, 28);
    const float h8 = rl(h, 32), h9 = rl(h, 36);
    float g2 = fmaf(h6, wh[6], h2*wh[2]);
    float g3 = fmaf(h7, wh[7], h3*wh[3]);
    g0 = fmaf(h8, wh[8], fmaf(h4_, wh[4], fmaf(h0, wh[0], g0)));
    g1 = fmaf(h9, wh[9], fmaf(h5, wh[5], fmaf(h1, wh[1], g1)));
    const float g = (g0 + g2) + (g1 + g3);
    const float s = fmaf(frcp(1.f + fexp2(g)), aa, bb);
    const float si = dppb<0x00>(s);
    const float sf = dppb<0x55>(s);
    const float tg = dppb<0xAA>(s);
    const float so = dppb<0xFF>(s);
    c = fmaf(sf, c, si*tg);
    h = so * fmaf(frcp(1.f + fexp2(km2*c)), 2.f, -1.f);
    pj = pjn;
  }

  // ---- edge LSTM backward at t=-1: single step from zero state ----
  const float wxb = ew_b[row*2] * m, wyb = ew_b[row*2+1] * m;
  const float cstb = (ebi_b[row] + ebh_b[row]) * m;
  const float2 pl = pbuf[1023];
  const float gB = fmaf(pl.x - pix, wxb, fmaf(pl.y - piy, wyb, cstb));
  float sB = fmaf(frcp(1.f + fexp2(gB)), aa, bb);
  const float siB = dppb<0x00>(sB);
  const float tgB = dppb<0xAA>(sB);
  const float soB = dppb<0xFF>(sB);
  const float cB = siB * tgB;
  const float hB = soB * tanhf_(cB);
  if (q == 0 && l < 40) {
    catted[b*180 + 160 + k] = h;
    catted[b*180 + 170 + k] = hB;
  }
}

// ---------------------------------------------------------------------------
// Kernel 2: GRU scan (12 steps) + heads + sampling.
// 768 threads, 4 batches/block, grid 256. Thread (jg,kc) owns 4 gate rows x
// 16 k's: 64 weights = 16 float4 in VGPRs (NO spill), 4x h-reuse cuts LDS
// read volume 4x vs one-row-per-thread. k-partials combine via pg[8][384][4]
// (16B read stride = full LDS BW).
// ---------------------------------------------------------------------------
#define GB 4
__global__ __launch_bounds__(768) void gru_kernel(
    const float* __restrict__ catted, const float* __restrict__ a0,
    const float* __restrict__ eps,
    const float* __restrict__ gw, const float* __restrict__ gu,
    const float* __restrict__ gbi, const float* __restrict__ gbh,
    const float* __restrict__ sw, const float* __restrict__ sb,
    const float* __restrict__ pw, const float* __restrict__ pb,
    const float* __restrict__ mw, const float* __restrict__ mb,
    const float* __restrict__ lw, const float* __restrict__ lb,
    const float* __restrict__ cw, const float* __restrict__ cb,
    float* __restrict__ out)
{
  __shared__ __align__(16) float cat4[GB][184];
  __shared__ __align__(16) float h4[128][GB];
  __shared__ __align__(16) float pg[8][384][GB];
  __shared__ __align__(16) float GcF[384][GB];
  __shared__ __align__(16) float head6[6][GB];
  __shared__ float a_l[GB][2];
  const int tid = threadIdx.x;
  const int b0 = blockIdx.x * GB;

  // ---- load catted (4 rows) + a0 ----
  {
    for (int idx = tid; idx < GB*180; idx += 768) {
      const int bb2 = idx / 180, kk = idx - bb2*180;
      cat4[bb2][kk] = catted[b0*180 + idx];
    }
    if (tid < GB*2) a_l[tid >> 1][tid & 1] = a0[b0*2 + tid];
  }

  // ---- per-thread weight tile: 4 rows x 16 k ----
  const int jg = tid >> 3, kc = tid & 7;
  const int jbase = jg * 4;
  float4 w4[4][4];
  {
    const float* gup = gu + jbase*128 + kc*16;
    #pragma unroll
    for (int r = 0; r < 4; ++r)
      #pragma unroll
      for (int i = 0; i < 4; ++i)
        w4[r][i] = *(const float4*)(gup + r*128 + i*4);
  }
  float gbh4[4];
  #pragma unroll
  for (int r = 0; r < 4; ++r) gbh4[r] = (kc == 0) ? gbh[jbase + r] : 0.f;

  // head-phase constants (waves 0..5)
  const int w = tid >> 6, lane = tid & 63;
  float hwlo = 0.f, hwhi = 0.f, hbias = 0.f;
  if      (w == 0) { hwlo = pw[lane];     hwhi = pw[64+lane];  hbias = pb[0]; }
  else if (w == 1) { hwlo = mw[lane];     hwhi = mw[64+lane];  hbias = mb[0]; }
  else if (w == 2) { hwlo = mw[128+lane]; hwhi = mw[192+lane]; hbias = mb[1]; }
  else if (w == 3) { hwlo = lw[lane];     hwhi = lw[64+lane];  hbias = lb[0]; }
  else if (w == 4) { hwlo = lw[128+lane]; hwhi = lw[192+lane]; hbias = lb[1]; }
  else if (w == 5) { hwlo = cw[lane];     hwhi = cw[64+lane];  hbias = cb[0]; }

  // gate-phase a-weights (tid<128): rows j, 128+j, 256+j, cols 180..181
  float gaR0=0,gaR1=0,gaZ0=0,gaZ1=0,gaN0=0,gaN1=0;
  if (tid < 128) {
    gaR0 = gw[tid*182 + 180];        gaR1 = gw[tid*182 + 181];
    gaZ0 = gw[(128+tid)*182 + 180];  gaZ1 = gw[(128+tid)*182 + 181];
    gaN0 = gw[(256+tid)*182 + 180];  gaN1 = gw[(256+tid)*182 + 181];
  }

  __syncthreads();

  // ---- Gc halves (all threads) + state0 halves (tid<256) ----
  {
    const int half = (tid >= 384) ? 1 : 0;
    const int j = tid - half*384;
    float p0[GB] = {0.f, 0.f, 0.f, 0.f};
    const float* gwr = gw + j*182 + half*90;
    for (int kk = 0; kk < 90; kk += 2) {
      const float2 w2 = *(const float2*)(gwr + kk);
      #pragma unroll
      for (int bb2 = 0; bb2 < GB; bb2++)
        p0[bb2] = fmaf(w2.x, cat4[bb2][half*90+kk], fmaf(w2.y, cat4[bb2][half*90+kk+1], p0[bb2]));
    }
    *(float4*)&pg[half][j][0] = make_float4(p0[0], p0[1], p0[2], p0[3]);
  }
  if (tid < 256) {
    const int half = tid >> 7;
    const int j2 = tid & 127;
    float p0[GB] = {0.f, 0.f, 0.f, 0.f};
    const float* swr = sw + j2*180 + half*90;
    for (int kk = 0; kk < 90; kk += 2) {
      const float2 w2 = *(const float2*)(swr + kk);
      #pragma unroll
      for (int bb2 = 0; bb2 < GB; bb2++)
        p0[bb2] = fmaf(w2.x, cat4[bb2][half*90+kk], fmaf(w2.y, cat4[bb2][half*90+kk+1], p0[bb2]));
    }
    *(float4*)&pg[2+half][j2][0] = make_float4(p0[0], p0[1], p0[2], p0[3]);
  }
  __syncthreads();
  if (tid < 384) {
    const float gb = gbi[tid];
    #pragma unroll
    for (int bb2 = 0; bb2 < GB; bb2++)
      GcF[tid][bb2] = pg[0][tid][bb2] + pg[1][tid][bb2] + gb;
  } else if (tid < 512) {
    const int j2 = tid - 384;
    const float sbb = sb[j2];
    #pragma unroll
    for (int bb2 = 0; bb2 < GB; bb2++)
      h4[j2][bb2] = pg[2][j2][bb2] + pg[3][j2][bb2] + sbb;
  }
  __syncthreads();

  // ---- 12-step GRU scan ----
  for (int t = 0; t < 12; t++) {
    // phase A: gh partials, all 768 threads
    {
      float acc[4][GB];
      #pragma unroll
      for (int r = 0; r < 4; ++r)
        #pragma unroll
        for (int bb2 = 0; bb2 < GB; bb2++) acc[r][bb2] = gbh4[r];
      #pragma unroll
      for (int i = 0; i < 4; ++i) {
        const int kb = kc*16 + i*4;
        const float4 ha = *(const float4*)&h4[kb+0][0];
        const float4 hb = *(const float4*)&h4[kb+1][0];
        const float4 hc = *(const float4*)&h4[kb+2][0];
        const float4 hd = *(const float4*)&h4[kb+3][0];
        #pragma unroll
        for (int r = 0; r < 4; ++r) {
          const float4 wv = w4[r][i];
          acc[r][0] = fmaf(wv.x, ha.x, acc[r][0]); acc[r][1] = fmaf(wv.x, ha.y, acc[r][1]);
          acc[r][2] = fmaf(wv.x, ha.z, acc[r][2]); acc[r][3] = fmaf(wv.x, ha.w, acc[r][3]);
          acc[r][0] = fmaf(wv.y, hb.x, acc[r][0]); acc[r][1] = fmaf(wv.y, hb.y, acc[r][1]);
          acc[r][2] = fmaf(wv.y, hb.z, acc[r][2]); acc[r][3] = fmaf(wv.y, hb.w, acc[r][3]);
          acc[r][0] = fmaf(wv.z, hc.x, acc[r][0]); acc[r][1] = fmaf(wv.z, hc.y, acc[r][1]);
          acc[r][2] = fmaf(wv.z, hc.z, acc[r][2]); acc[r][3] = fmaf(wv.z, hc.w, acc[r][3]);
          acc[r][0] = fmaf(wv.w, hd.x, acc[r][0]); acc[r][1] = fmaf(wv.w, hd.y, acc[r][1]);
          acc[r][2] = fmaf(wv.w, hd.z, acc[r][2]); acc[r][3] = fmaf(wv.w, hd.w, acc[r][3]);
        }
      }
      #pragma unroll
      for (int r = 0; r < 4; ++r)
        *(float4*)&pg[kc][jbase + r][0] = make_float4(acc[r][0], acc[r][1], acc[r][2], acc[r][3]);
    }
    __syncthreads();

    // phase B: combine partials + gate nonlinearities (tid<128)
    if (tid < 128) {
      const int j = tid;
      float ghr[4] = {0,0,0,0}, ghz[4] = {0,0,0,0}, ghn[4] = {0,0,0,0};
      #pragma unroll
      for (int kc2 = 0; kc2 < 8; ++kc2) {
        const float4 t0 = *(const float4*)&pg[kc2][j][0];
        const float4 t1 = *(const float4*)&pg[kc2][128+j][0];
        const float4 t2 = *(const float4*)&pg[kc2][256+j][0];
        ghr[0]+=t0.x; ghr[1]+=t0.y; ghr[2]+=t0.z; ghr[3]+=t0.w;
        ghz[0]+=t1.x; ghz[1]+=t1.y; ghz[2]+=t1.z; ghz[3]+=t1.w;
        ghn[0]+=t2.x; ghn[1]+=t2.y; ghn[2]+=t2.z; ghn[3]+=t2.w;
      }
      const float4 GcR = *(const float4*)&GcF[j][0];
      const float4 GcZ = *(const float4*)&GcF[128+j][0];
      const float4 GcN = *(const float4*)&GcF[256+j][0];
      const float gcr[4] = {GcR.x, GcR.y, GcR.z, GcR.w};
      const float gcz[4] = {GcZ.x, GcZ.y, GcZ.z, GcZ.w};
      const float gcn[4] = {GcN.x, GcN.y, GcN.z, GcN.w};
      const float4 hold4 = *(const float4*)&h4[j][0];
      const float hold[4] = {hold4.x, hold4.y, hold4.z, hold4.w};
      float hn[4];
      #pragma unroll
      for (int bb2 = 0; bb2 < GB; bb2++) {
        const float ax = a_l[bb2][0], ay = a_l[bb2][1];
        const float gi_r = fmaf(gaR0, ax, fmaf(gaR1, ay, gcr[bb2]));
        const float gi_z = fmaf(gaZ0, ax, fmaf(gaZ1, ay, gcz[bb2]));
        const float gi_n = fmaf(gaN0, ax, fmaf(gaN1, ay, gcn[bb2]));
        const float r = sigm(gi_r + ghr[bb2]);
        const float z = sigm(gi_z + ghz[bb2]);
        const float n = tanhf_(fmaf(r, ghn[bb2], gi_n));
        hn[bb2] = fmaf(z, hold[bb2] - n, n);
      }
      *(float4*)&h4[j][0] = make_float4(hn[0], hn[1], hn[2], hn[3]);
    }
    __syncthreads();

    // phase C: heads (waves 0..5)
    if (tid < 384) {
      const float4 hlo = *(const float4*)&h4[lane][0];
      const float4 hhi = *(const float4*)&h4[64+lane][0];
      float v0 = fmaf(hwlo, hlo.x, hwhi*hhi.x);
      float v1 = fmaf(hwlo, hlo.y, hwhi*hhi.y);
      float v2 = fmaf(hwlo, hlo.z, hwhi*hhi.z);
      float v3 = fmaf(hwlo, hlo.w, hwhi*hhi.w);
      #pragma unroll
      for (int off = 32; off > 0; off >>= 1) {
        v0 += __shfl_xor(v0, off, 64);
        v1 += __shfl_xor(v1, off, 64);
        v2 += __shfl_xor(v2, off, 64);
        v3 += __shfl_xor(v3, off, 64);
      }
      if (lane == 0)
        *(float4*)&head6[w][0] = make_float4(v0+hbias, v1+hbias, v2+hbias, v3+hbias);
    }
    __syncthreads();

    // phase D: output + sampling (tid<GB)
    if (tid < GB) {
      const int gb2 = b0 + tid;
      const float p  = head6[0][tid];
      const float m0 = head6[1][tid];
      const float m1 = head6[2][tid];
      const float l0 = head6[3][tid];
      const float l1 = head6[4][tid];
      const float cr = tanhf_(head6[5][tid]);
      float* ob = out + ((size_t)t*1024 + gb2)*6;
      *(float2*)(ob + 0) = make_float2(p,  m0);
      *(float2*)(ob + 2) = make_float2(m1, l0);
      *(float2*)(ob + 4) = make_float2(l1, cr);
      const float e0 = eps[(t*1024 + gb2)*2 + 0];
      const float e1 = eps[(t*1024 + gb2)*2 + 1];
      const float sx = fexp2(l0 * LOG2E);
      const float sy = fexp2(l1 * LOG2E);
      const float rt = sqrtf(fmaxf(1.f - cr*cr, 1e-12f));
      a_l[tid][0] = fmaf(sx, e0, m0);
      a_l[tid][1] = fmaf(sy, fmaf(cr, e0, rt*e1), m1);
    }
    __syncthreads();
  }
}

extern "C" void kernel_launch(void* const* d_in, const int* in_sizes, int n_in,
                              void* d_out, int out_size, void* d_ws, size_t ws_size,
                              hipStream_t stream) {
  const float* scene = (const float*)d_in[0];
  const float* eps   = (const float*)d_in[1];
  const float* nw_f  = (const float*)d_in[2];
  const float* nu_f  = (const float*)d_in[3];
  const float* nbi_f = (const float*)d_in[4];
  const float* nbh_f = (const float*)d_in[5];
  const float* nw_b  = (const float*)d_in[6];
  const float* nu_b  = (const float*)d_in[7];
  const float* nbi_b = (const float*)d_in[8];
  const float* nbh_b = (const float*)d_in[9];
  const float* ew_f  = (const float*)d_in[10];
  const float* eu_f  = (const float*)d_in[11];
  const float* ebi_f = (const float*)d_in[12];
  const float* ebh_f = (const float*)d_in[13];
  const float* ew_b  = (const float*)d_in[14];
  const float* eu_b  = (const float*)d_in[15];
  const float* ebi_b = (const float*)d_in[16];
  const float* ebh_b = (const float*)d_in[17];
  const float* gw    = (const float*)d_in[18];
  const float* gu    = (const float*)d_in[19];
  const float* gbi   = (const float*)d_in[20];
  const float* gbh   = (const float*)d_in[21];
  const float* aw    = (const float*)d_in[22];
  const float* ab    = (const float*)d_in[23];
  const float* sw    = (const float*)d_in[24];
  const float* sb    = (const float*)d_in[25];
  const float* pw    = (const float*)d_in[26];
  const float* pb    = (const float*)d_in[27];
  const float* mw    = (const float*)d_in[28];
  const float* mb    = (const float*)d_in[29];
  const float* lw    = (const float*)d_in[30];
  const float* lb    = (const float*)d_in[31];
  const float* cw    = (const float*)d_in[32];
  const float* cb    = (const float*)d_in[33];

  float* catted = (float*)d_ws;                           // 1024*180*4 = 737280 B
  float* a0p    = (float*)((char*)d_ws + 737280);         // 1024*2*4   =   8192 B

  enc_kernel<<<1024, 64, 0, stream>>>(scene,
                                      nw_f, nu_f, nbi_f, nbh_f,
                                      nw_b, nu_b, nbi_b, nbh_b,
                                      ew_f, eu_f, ebi_f, ebh_f,
                                      ew_b, eu_b, ebi_b, ebh_b,
                                      aw, ab, catted, a0p);
  gru_kernel<<<256, 768, 0, stream>>>(catted, a0p, eps, gw, gu, gbi, gbh,
                                      sw, sb, pw, pb, mw, mb, lw, lb, cw, cb,
                                      (float*)d_out);
}